// Round 3
// baseline (395.886 us; speedup 1.0000x reference)
//
#include <hip/hip_runtime.h>
#include <stdint.h>

#pragma clang fp contract(off)

#define BB 4
#define NN 2000
#define GG 100
#define HIMG 1024
#define WIMG 1024
#define PPOS 66
#define PNEG 134
#define TT 200
#define MH 28
#define MW 28

// output offsets (floats): rois [B,200,4], ids [B,200], deltas [B,200,4], masks [B,200,28,28]
#define OFF_ROIS 0
#define OFF_IDS  (BB*TT*4)                    // 3200
#define OFF_DELT (BB*TT*4 + BB*TT)            // 4000
#define OFF_MASK (BB*TT*4 + BB*TT + BB*TT*4)  // 7200

// ws layout per image b (ints, stride 512): [0]=npos [1]=nneg [2..67]=pos_idx [68..133]=assign
#define WS_STRIDE 512

__device__ __forceinline__ void tf2x32(uint32_t k0, uint32_t k1, uint32_t& x0, uint32_t& x1){
  uint32_t ks2 = k0 ^ k1 ^ 0x1BD11BDAu;
  x0 += k0; x1 += k1;
#define TFR(r) { x0 += x1; x1 = (x1 << r) | (x1 >> (32 - r)); x1 ^= x0; }
  TFR(13) TFR(15) TFR(26) TFR(6)
  x0 += k1;  x1 += ks2 + 1u;
  TFR(17) TFR(29) TFR(16) TFR(24)
  x0 += ks2; x1 += k0 + 2u;
  TFR(13) TFR(15) TFR(26) TFR(6)
  x0 += k0;  x1 += k1 + 3u;
  TFR(17) TFR(29) TFR(16) TFR(24)
  x0 += k1;  x1 += ks2 + 4u;
  TFR(13) TFR(15) TFR(26) TFR(6)
  x0 += ks2; x1 += k0 + 5u;
#undef TFR
}

__device__ __forceinline__ float u01(uint32_t b){
  return __uint_as_float((b >> 9) | 0x3f800000u) - 1.0f;
}

__device__ __forceinline__ float iou1(float py1, float px1, float py2, float px2,
                                      const float* __restrict__ g){
  float y1 = fmaxf(py1, g[0]);
  float x1 = fmaxf(px1, g[1]);
  float y2 = fminf(py2, g[2]);
  float x2 = fminf(px2, g[3]);
  float inter = fmaxf(x2 - x1, 0.0f) * fmaxf(y2 - y1, 0.0f);
  float a1 = (py2 - py1) * (px2 - px1);
  float a2 = (g[2] - g[0]) * (g[3] - g[1]);
  return inter / (a1 + a2 - inter);
}

__global__ void dtl_zero(float* __restrict__ out, int n){
  int i = blockIdx.x * 256 + threadIdx.x;
  if (i < n) out[i] = 0.0f;
}

__global__ __launch_bounds__(256) void dtl_main(
    const float* __restrict__ props, const int* __restrict__ gids,
    const float* __restrict__ gboxes, float* __restrict__ out,
    int* __restrict__ ws)
{
  const int b = blockIdx.x;
  const int t = threadIdx.x;
  __shared__ float sPos[NN];
  __shared__ float sNeg[NN];
  __shared__ float sGt[GG*4];
  __shared__ int   sGid[GG];
  __shared__ float sRedV[4];
  __shared__ int   sRedI[4];
  __shared__ int   sPosIdx[PPOS];
  __shared__ int   sNegIdx[PNEG];
  __shared__ int   sCnt[2];

  const float* pb = props + b*NN*4;

  if (t == 0){ sCnt[0] = 0; sCnt[1] = 0; }
  for (int i = t; i < GG; i += 256){
    sGid[i] = gids[b*GG + i];
    sGt[i*4+0] = gboxes[(b*GG+i)*4+0];
    sGt[i*4+1] = gboxes[(b*GG+i)*4+1];
    sGt[i*4+2] = gboxes[(b*GG+i)*4+2];
    sGt[i*4+3] = gboxes[(b*GG+i)*4+3];
  }
  __syncthreads();

  // ---- JAX threefry key derivation (jax_threefry_partitionable=True, JAX >= 0.5) ----
  // root = key(42) = (0,42)
  // split(root,4): keys[b] = both output words of TF(root, (hi=0, lo=b))
  // split(keys[b],2): k1 = TF(keyb,(0,0)), k2 = TF(keyb,(0,1))
  uint32_t k1a, k1b, k2a, k2b;
  {
    uint32_t ia = 0u, ib = (uint32_t)b;
    tf2x32(0u, 42u, ia, ib);              // imgkey = (ia, ib)
    uint32_t a0 = 0u, c0 = 0u; tf2x32(ia, ib, a0, c0);
    uint32_t a1 = 0u, c1 = 1u; tf2x32(ia, ib, a1, c1);
    k1a = a0; k1b = c0;
    k2a = a1; k2b = c1;
  }

  // uniform scores (partitionable random_bits): bits[i] = xor of
  // both output words of TF(k, (hi=0, lo=i))
  for (int i = t; i < NN; i += 256){
    uint32_t a = 0u, c = (uint32_t)i;
    tf2x32(k1a, k1b, a, c);
    sPos[i] = u01(a ^ c);
    uint32_t a2 = 0u, c2 = (uint32_t)i;
    tf2x32(k2a, k2b, a2, c2);
    sNeg[i] = u01(a2 ^ c2);
  }
  __syncthreads();

  // eligibility + score gating
  int myPos = 0, myNeg = 0;
  for (int i = t; i < NN; i += 256){
    float py1 = pb[i*4+0], px1 = pb[i*4+1], py2 = pb[i*4+2], px2 = pb[i*4+3];
    float best = -1.0f, cbest = -1.0f;
    for (int g = 0; g < GG; ++g){
      float v = iou1(py1, px1, py2, px2, &sGt[g*4]);
      int id = sGid[g];
      if (id > 0) best = fmaxf(best, v);
      else if (id < 0) cbest = fmaxf(cbest, v);
    }
    bool noc  = cbest < 1e-3f;
    bool posb = best >= 0.5f;
    bool negb = (best < 0.5f) && noc;
    myPos += posb ? 1 : 0;
    myNeg += negb ? 1 : 0;
    if (!posb) sPos[i] = -1.0f;
    if (!negb) sNeg[i] = -1.0f;
  }
  // counts (wave reduce + LDS atomics)
  int vp = myPos, vn = myNeg;
  for (int off = 32; off; off >>= 1){
    vp += __shfl_down(vp, off);
    vn += __shfl_down(vn, off);
  }
  if ((t & 63) == 0){ atomicAdd(&sCnt[0], vp); atomicAdd(&sCnt[1], vn); }
  __syncthreads();
  const int posCount = sCnt[0], negCount = sCnt[1];
  const int npos = min(posCount, PPOS);
  int tgt = (int)((float)npos / 0.33f) - npos;  // exact fp32 semantics of reference
  if (tgt < 0) tgt = 0;
  const int nneg = min(min(negCount, tgt), PNEG);

  // top-k selection = iterative block argmax (ties: lower index, matches lax.top_k)
  for (int k = 0; k < npos; ++k){
    float bv = -2.0f; int bi = NN;
    for (int i = t; i < NN; i += 256){
      float v = sPos[i];
      if (v > bv){ bv = v; bi = i; }
    }
    for (int off = 32; off; off >>= 1){
      float ov2 = __shfl_down(bv, off);
      int   oi2 = __shfl_down(bi, off);
      if (ov2 > bv || (ov2 == bv && oi2 < bi)){ bv = ov2; bi = oi2; }
    }
    if ((t & 63) == 0){ sRedV[t >> 6] = bv; sRedI[t >> 6] = bi; }
    __syncthreads();
    if (t == 0){
      float Bv = sRedV[0]; int Bi = sRedI[0];
      for (int wq = 1; wq < 4; ++wq){
        float v = sRedV[wq]; int i2 = sRedI[wq];
        if (v > Bv || (v == Bv && i2 < Bi)){ Bv = v; Bi = i2; }
      }
      sPosIdx[k] = Bi;
      sPos[Bi] = -3.0f;
    }
    __syncthreads();
  }
  for (int k = 0; k < nneg; ++k){
    float bv = -2.0f; int bi = NN;
    for (int i = t; i < NN; i += 256){
      float v = sNeg[i];
      if (v > bv){ bv = v; bi = i; }
    }
    for (int off = 32; off; off >>= 1){
      float ov2 = __shfl_down(bv, off);
      int   oi2 = __shfl_down(bi, off);
      if (ov2 > bv || (ov2 == bv && oi2 < bi)){ bv = ov2; bi = oi2; }
    }
    if ((t & 63) == 0){ sRedV[t >> 6] = bv; sRedI[t >> 6] = bi; }
    __syncthreads();
    if (t == 0){
      float Bv = sRedV[0]; int Bi = sRedI[0];
      for (int wq = 1; wq < 4; ++wq){
        float v = sRedV[wq]; int i2 = sRedI[wq];
        if (v > Bv || (v == Bv && i2 < Bi)){ Bv = v; Bi = i2; }
      }
      sNegIdx[k] = Bi;
      sNeg[Bi] = -3.0f;
    }
    __syncthreads();
  }

  // positive outputs: rois, ids, deltas + ws for mask kernel
  if (t < npos){
    int idx = sPosIdx[t];
    float py1 = pb[idx*4+0], px1 = pb[idx*4+1], py2 = pb[idx*4+2], px2 = pb[idx*4+3];
    // argmax over non-crowd gts, first occurrence of max
    float bestv = -2.0f; int bg = 0;
    for (int g = 0; g < GG; ++g){
      float v = (sGid[g] > 0) ? iou1(py1, px1, py2, px2, &sGt[g*4]) : -1.0f;
      if (v > bestv){ bestv = v; bg = g; }
    }
    const float* gt = &sGt[bg*4];
    float h  = py2 - py1,        w  = px2 - px1;
    float cy = py1 + 0.5f*h,     cx = px1 + 0.5f*w;
    float gh = gt[2] - gt[0],    gw = gt[3] - gt[1];
    float gcy = gt[0] + 0.5f*gh, gcx = gt[1] + 0.5f*gw;
    float d0 = ((gcy - cy) / h) / 0.1f;
    float d1 = ((gcx - cx) / w) / 0.1f;
    float d2 = logf(gh / h) / 0.2f;
    float d3 = logf(gw / w) / 0.2f;
    float* ro = out + OFF_ROIS + (b*TT + t)*4;
    ro[0] = py1; ro[1] = px1; ro[2] = py2; ro[3] = px2;
    out[OFF_IDS + b*TT + t] = (float)sGid[bg];
    float* de = out + OFF_DELT + (b*TT + t)*4;
    de[0] = d0; de[1] = d1; de[2] = d2; de[3] = d3;
    ws[b*WS_STRIDE + 2 + t]  = idx;
    ws[b*WS_STRIDE + 68 + t] = bg;
  }
  // negative rois
  for (int p = t; p < nneg; p += 256){
    int idx = sNegIdx[p];
    float* ro = out + OFF_ROIS + (b*TT + PPOS + p)*4;
    ro[0] = pb[idx*4+0]; ro[1] = pb[idx*4+1];
    ro[2] = pb[idx*4+2]; ro[3] = pb[idx*4+3];
  }
  if (t == 0){ ws[b*WS_STRIDE] = npos; ws[b*WS_STRIDE + 1] = nneg; }
}

__global__ __launch_bounds__(256) void dtl_masks(
    const float* __restrict__ props, const unsigned char* __restrict__ gmask,
    const int* __restrict__ ws, float* __restrict__ out)
{
  const int p = blockIdx.x;   // slot 0..65
  const int b = blockIdx.y;
  const int npos = ws[b*WS_STRIDE];
  if (p >= npos) return;      // invalid slots stay zero
  const int t = threadIdx.x;
  __shared__ int   iy0[MH], iy1[MH], ix0[MW], ix1[MW];
  __shared__ float fy[MH], fx[MW];
  __shared__ float sbox[4];
  if (t == 0){
    int idx = ws[b*WS_STRIDE + 2 + p];
    sbox[0] = props[(b*NN + idx)*4 + 0];
    sbox[1] = props[(b*NN + idx)*4 + 1];
    sbox[2] = props[(b*NN + idx)*4 + 2];
    sbox[3] = props[(b*NN + idx)*4 + 3];
  }
  __syncthreads();
  if (t < MH){
    float y1 = sbox[0], y2 = sbox[2];
    float stepy = (y2 - y1) * 1023.0f / 27.0f;
    float ys = y1 * 1023.0f + (float)t * stepy;
    float y0f = floorf(ys);
    iy0[t] = (int)fminf(fmaxf(y0f, 0.0f), 1023.0f);
    iy1[t] = (int)fminf(fmaxf(y0f + 1.0f, 0.0f), 1023.0f);
    fy[t] = ys - y0f;
    float x1 = sbox[1], x2 = sbox[3];
    float stepx = (x2 - x1) * 1023.0f / 27.0f;
    float xs = x1 * 1023.0f + (float)t * stepx;
    float x0f = floorf(xs);
    ix0[t] = (int)fminf(fmaxf(x0f, 0.0f), 1023.0f);
    ix1[t] = (int)fminf(fmaxf(x0f + 1.0f, 0.0f), 1023.0f);
    fx[t] = xs - x0f;
  }
  __syncthreads();
  const int g = ws[b*WS_STRIDE + 68 + p];
  const unsigned char* mb = gmask + (size_t)b * HIMG * WIMG * GG + g;
  float* mo = out + OFF_MASK + (size_t)(b*TT + p) * (MH*MW);
  for (int pix = t; pix < MH*MW; pix += 256){
    int r = pix / MW, c = pix - r*MW;
    size_t ro0 = (size_t)iy0[r] * WIMG;
    size_t ro1 = (size_t)iy1[r] * WIMG;
    float v00 = mb[(ro0 + (size_t)ix0[c]) * GG] ? 1.0f : 0.0f;
    float v01 = mb[(ro0 + (size_t)ix1[c]) * GG] ? 1.0f : 0.0f;
    float v10 = mb[(ro1 + (size_t)ix0[c]) * GG] ? 1.0f : 0.0f;
    float v11 = mb[(ro1 + (size_t)ix1[c]) * GG] ? 1.0f : 0.0f;
    float fxx = fx[c], fyy = fy[r];
    float top = v00 * (1.0f - fxx) + v01 * fxx;
    float bot = v10 * (1.0f - fxx) + v11 * fxx;
    float val = top * (1.0f - fyy) + bot * fyy;
    mo[pix] = rintf(val);   // round half-to-even, matches jnp.round
  }
}

extern "C" void kernel_launch(void* const* d_in, const int* in_sizes, int n_in,
                              void* d_out, int out_size, void* d_ws, size_t ws_size,
                              hipStream_t stream){
  const float* props  = (const float*)d_in[0];
  const int*   gids   = (const int*)d_in[1];
  const float* gboxes = (const float*)d_in[2];
  const unsigned char* gmask = (const unsigned char*)d_in[3];
  float* out = (float*)d_out;
  int* ws = (int*)d_ws;

  dtl_zero<<<(out_size + 255)/256, 256, 0, stream>>>(out, out_size);
  dtl_main<<<BB, 256, 0, stream>>>(props, gids, gboxes, out, ws);
  dim3 mg(PPOS, BB);
  dtl_masks<<<mg, 256, 0, stream>>>(props, gmask, ws, out);
}

// Round 4
// 147.752 us; speedup vs baseline: 2.6794x; 2.6794x over previous
//
#include <hip/hip_runtime.h>
#include <stdint.h>

#pragma clang fp contract(off)

#define BB 4
#define NN 2000
#define GG 100
#define HIMG 1024
#define WIMG 1024
#define PPOS 66
#define PNEG 134
#define TT 200
#define MH 28
#define MW 28
#define CHUNK 250   // props per block in score/rank kernels (8 chunks)

// output offsets (floats): rois [B,200,4], ids [B,200], deltas [B,200,4], masks [B,200,28,28]
#define OFF_ROIS 0
#define OFF_IDS  (BB*TT*4)
#define OFF_DELT (BB*TT*4 + BB*TT)
#define OFF_MASK (BB*TT*4 + BB*TT + BB*TT*4)

// ws layout (int/float units)
#define WS_SCP(b)  ((b)*2048)            // 2000 floats: gated pos scores
#define WS_SCN(b)  (8192 + (b)*2048)     // 2000 floats: gated neg scores
#define WS_CNT     16384                 // ints: [b*4]=npos [b*4+1]=nneg
#define WS_PIDX(b) (16512 + (b)*128)     // ints: pos slot -> prop idx
#define WS_NIDX(b) (17024 + (b)*256)     // ints: neg slot -> prop idx
#define WS_ASG(b)  (18048 + (b)*128)     // ints: pos slot -> gt idx

__device__ __forceinline__ void tf2x32(uint32_t k0, uint32_t k1, uint32_t& x0, uint32_t& x1){
  uint32_t ks2 = k0 ^ k1 ^ 0x1BD11BDAu;
  x0 += k0; x1 += k1;
#define TFR(r) { x0 += x1; x1 = (x1 << r) | (x1 >> (32 - r)); x1 ^= x0; }
  TFR(13) TFR(15) TFR(26) TFR(6)
  x0 += k1;  x1 += ks2 + 1u;
  TFR(17) TFR(29) TFR(16) TFR(24)
  x0 += ks2; x1 += k0 + 2u;
  TFR(13) TFR(15) TFR(26) TFR(6)
  x0 += k0;  x1 += k1 + 3u;
  TFR(17) TFR(29) TFR(16) TFR(24)
  x0 += k1;  x1 += ks2 + 4u;
  TFR(13) TFR(15) TFR(26) TFR(6)
  x0 += ks2; x1 += k0 + 5u;
#undef TFR
}

__device__ __forceinline__ float u01(uint32_t b){
  return __uint_as_float((b >> 9) | 0x3f800000u) - 1.0f;
}

// derive per-image score keys (partitionable threefry, JAX >= 0.5)
__device__ __forceinline__ void img_keys(int b, uint32_t& k1a, uint32_t& k1b,
                                         uint32_t& k2a, uint32_t& k2b){
  uint32_t ia = 0u, ib = (uint32_t)b;
  tf2x32(0u, 42u, ia, ib);
  uint32_t a0 = 0u, c0 = 0u; tf2x32(ia, ib, a0, c0);
  uint32_t a1 = 0u, c1 = 1u; tf2x32(ia, ib, a1, c1);
  k1a = a0; k1b = c0; k2a = a1; k2b = c1;
}

__device__ __forceinline__ float iou2(float py1, float px1, float py2, float px2,
                                      float gy1, float gx1, float gy2, float gx2){
  float y1 = fmaxf(py1, gy1);
  float x1 = fmaxf(px1, gx1);
  float y2 = fminf(py2, gy2);
  float x2 = fminf(px2, gx2);
  float inter = fmaxf(x2 - x1, 0.0f) * fmaxf(y2 - y1, 0.0f);
  float a1 = (py2 - py1) * (px2 - px1);
  float a2 = (gy2 - gy1) * (gx2 - gx1);
  return inter / (a1 + a2 - inter);
}

__global__ void dtl_zero(float* __restrict__ out, int n){
  int i = blockIdx.x * 256 + threadIdx.x;
  if (i < n) out[i] = 0.0f;
}

// A: eligibility + gated scores. grid (8 chunks, 4 images) x 256
__global__ __launch_bounds__(256) void dtl_score(
    const float* __restrict__ props, const int* __restrict__ gids,
    const float* __restrict__ gboxes, float* __restrict__ wsF)
{
  const int cx = blockIdx.x, b = blockIdx.y;
  const int t = threadIdx.x;
  __shared__ float4 sGt[GG];
  __shared__ int    sGid[GG];
  if (t < GG){
    sGt[t]  = ((const float4*)(gboxes + b*GG*4))[t];
    sGid[t] = gids[b*GG + t];
  }
  __syncthreads();
  const int i = cx*CHUNK + t;
  if (t >= CHUNK || i >= NN) return;

  const float4 p = ((const float4*)(props + b*NN*4))[i];
  float best = -1.0f, cbest = -1.0f;
  for (int g = 0; g < GG; ++g){
    float4 gb = sGt[g];
    float v = iou2(p.x, p.y, p.z, p.w, gb.x, gb.y, gb.z, gb.w);
    int id = sGid[g];
    if (id > 0) best = fmaxf(best, v);
    else if (id < 0) cbest = fmaxf(cbest, v);
  }
  bool noc  = cbest < 1e-3f;
  bool posb = best >= 0.5f;
  bool negb = (best < 0.5f) && noc;

  uint32_t k1a, k1b, k2a, k2b;
  img_keys(b, k1a, k1b, k2a, k2b);
  uint32_t a = 0u, c = (uint32_t)i;
  tf2x32(k1a, k1b, a, c);
  uint32_t a2 = 0u, c2 = (uint32_t)i;
  tf2x32(k2a, k2b, a2, c2);
  wsF[WS_SCP(b) + i] = posb ? u01(a ^ c)   : -1.0f;
  wsF[WS_SCN(b) + i] = negb ? u01(a2 ^ c2) : -1.0f;
}

// B: parallel exact top-k via rank. grid (8 chunks, 2 arrays, 4 images) x 256
__global__ __launch_bounds__(256) void dtl_rank(
    const float* __restrict__ wsF, int* __restrict__ wsI)
{
  const int cx = blockIdx.x, arr = blockIdx.y, b = blockIdx.z;
  const int t = threadIdx.x;
  __shared__ float4 sS4[NN/4];
  const float* sc = wsF + (arr == 0 ? WS_SCP(b) : WS_SCN(b));
  for (int j = t; j < NN/4; j += 256)
    sS4[j] = ((const float4*)sc)[j];
  __syncthreads();
  const int i = cx*CHUNK + t;
  if (t >= CHUNK || i >= NN) return;
  const float* sS = (const float*)sS4;
  const float vi = sS[i];
  if (vi == -1.0f) return;   // ineligible
  int rank = 0;
  for (int j4 = 0; j4 < NN/4; ++j4){
    float4 w = sS4[j4];
    int j = 4*j4;
    rank += (int)((w.x > vi) | ((w.x == vi) & (j     < i)));
    rank += (int)((w.y > vi) | ((w.y == vi) & (j + 1 < i)));
    rank += (int)((w.z > vi) | ((w.z == vi) & (j + 2 < i)));
    rank += (int)((w.w > vi) | ((w.w == vi) & (j + 3 < i)));
  }
  const int cap = (arr == 0) ? PPOS : PNEG;
  if (rank < cap)
    wsI[(arr == 0 ? WS_PIDX(b) : WS_NIDX(b)) + rank] = i;
}

// C: counts + rois/ids/deltas. grid (4 images) x 256
__global__ __launch_bounds__(256) void dtl_emit(
    const float* __restrict__ props, const int* __restrict__ gids,
    const float* __restrict__ gboxes, const float* __restrict__ wsF,
    int* __restrict__ wsI, float* __restrict__ out)
{
  const int b = blockIdx.x;
  const int t = threadIdx.x;
  __shared__ float4 sGt[GG];
  __shared__ int    sGid[GG];
  __shared__ int    sCnt[2];
  if (t == 0){ sCnt[0] = 0; sCnt[1] = 0; }
  if (t < GG){
    sGt[t]  = ((const float4*)(gboxes + b*GG*4))[t];
    sGid[t] = gids[b*GG + t];
  }
  __syncthreads();
  int cp = 0, cn = 0;
  for (int j = t; j < NN; j += 256){
    cp += (wsF[WS_SCP(b) + j] != -1.0f);
    cn += (wsF[WS_SCN(b) + j] != -1.0f);
  }
  for (int off = 32; off; off >>= 1){
    cp += __shfl_down(cp, off);
    cn += __shfl_down(cn, off);
  }
  if ((t & 63) == 0){ atomicAdd(&sCnt[0], cp); atomicAdd(&sCnt[1], cn); }
  __syncthreads();
  const int posCount = sCnt[0], negCount = sCnt[1];
  const int npos = min(posCount, PPOS);
  int tgt = (int)((float)npos / 0.33f) - npos;   // exact fp32 semantics
  if (tgt < 0) tgt = 0;
  const int nneg = min(min(negCount, tgt), PNEG);
  if (t == 0){ wsI[WS_CNT + b*4] = npos; wsI[WS_CNT + b*4 + 1] = nneg; }

  const float* pb = props + b*NN*4;
  if (t < PPOS && t < npos){
    int idx = wsI[WS_PIDX(b) + t];
    float py1 = pb[idx*4+0], px1 = pb[idx*4+1], py2 = pb[idx*4+2], px2 = pb[idx*4+3];
    float bestv = -2.0f; int bg = 0;
    for (int g = 0; g < GG; ++g){
      float4 gb = sGt[g];
      float v = (sGid[g] > 0) ? iou2(py1, px1, py2, px2, gb.x, gb.y, gb.z, gb.w) : -1.0f;
      if (v > bestv){ bestv = v; bg = g; }
    }
    float4 gt = sGt[bg];
    float h  = py2 - py1,         w  = px2 - px1;
    float cy = py1 + 0.5f*h,      cx2 = px1 + 0.5f*w;
    float gh = gt.z - gt.x,       gw = gt.w - gt.y;
    float gcy = gt.x + 0.5f*gh,   gcx = gt.y + 0.5f*gw;
    float d0 = ((gcy - cy) / h) / 0.1f;
    float d1 = ((gcx - cx2) / w) / 0.1f;
    float d2 = logf(gh / h) / 0.2f;
    float d3 = logf(gw / w) / 0.2f;
    float* ro = out + OFF_ROIS + (b*TT + t)*4;
    ro[0] = py1; ro[1] = px1; ro[2] = py2; ro[3] = px2;
    out[OFF_IDS + b*TT + t] = (float)sGid[bg];
    float* de = out + OFF_DELT + (b*TT + t)*4;
    de[0] = d0; de[1] = d1; de[2] = d2; de[3] = d3;
    wsI[WS_ASG(b) + t] = bg;
  } else if (t >= PPOS && t < TT){
    int p = t - PPOS;
    if (p < nneg){
      int idx = wsI[WS_NIDX(b) + p];
      float* ro = out + OFF_ROIS + (b*TT + PPOS + p)*4;
      ro[0] = pb[idx*4+0]; ro[1] = pb[idx*4+1];
      ro[2] = pb[idx*4+2]; ro[3] = pb[idx*4+3];
    }
  }
}

// D: mask crop+resize. grid (66, 4) x 256
__global__ __launch_bounds__(256) void dtl_masks(
    const float* __restrict__ props, const unsigned char* __restrict__ gmask,
    const int* __restrict__ wsI, float* __restrict__ out)
{
  const int p = blockIdx.x;
  const int b = blockIdx.y;
  const int npos = wsI[WS_CNT + b*4];
  if (p >= npos) return;
  const int t = threadIdx.x;
  __shared__ int   iy0[MH], iy1[MH], ix0[MW], ix1[MW];
  __shared__ float fy[MH], fx[MW];
  __shared__ float sbox[4];
  if (t == 0){
    int idx = wsI[WS_PIDX(b) + p];
    sbox[0] = props[(b*NN + idx)*4 + 0];
    sbox[1] = props[(b*NN + idx)*4 + 1];
    sbox[2] = props[(b*NN + idx)*4 + 2];
    sbox[3] = props[(b*NN + idx)*4 + 3];
  }
  __syncthreads();
  if (t < MH){
    float y1 = sbox[0], y2 = sbox[2];
    float stepy = (y2 - y1) * 1023.0f / 27.0f;
    float ys = y1 * 1023.0f + (float)t * stepy;
    float y0f = floorf(ys);
    iy0[t] = (int)fminf(fmaxf(y0f, 0.0f), 1023.0f);
    iy1[t] = (int)fminf(fmaxf(y0f + 1.0f, 0.0f), 1023.0f);
    fy[t] = ys - y0f;
    float x1 = sbox[1], x2 = sbox[3];
    float stepx = (x2 - x1) * 1023.0f / 27.0f;
    float xs = x1 * 1023.0f + (float)t * stepx;
    float x0f = floorf(xs);
    ix0[t] = (int)fminf(fmaxf(x0f, 0.0f), 1023.0f);
    ix1[t] = (int)fminf(fmaxf(x0f + 1.0f, 0.0f), 1023.0f);
    fx[t] = xs - x0f;
  }
  __syncthreads();
  const int g = wsI[WS_ASG(b) + p];
  const unsigned char* mb = gmask + (size_t)b * HIMG * WIMG * GG + g;
  float* mo = out + OFF_MASK + (size_t)(b*TT + p) * (MH*MW);
  for (int pix = t; pix < MH*MW; pix += 256){
    int r = pix / MW, c = pix - r*MW;
    size_t ro0 = (size_t)iy0[r] * WIMG;
    size_t ro1 = (size_t)iy1[r] * WIMG;
    float v00 = mb[(ro0 + (size_t)ix0[c]) * GG] ? 1.0f : 0.0f;
    float v01 = mb[(ro0 + (size_t)ix1[c]) * GG] ? 1.0f : 0.0f;
    float v10 = mb[(ro1 + (size_t)ix0[c]) * GG] ? 1.0f : 0.0f;
    float v11 = mb[(ro1 + (size_t)ix1[c]) * GG] ? 1.0f : 0.0f;
    float fxx = fx[c], fyy = fy[r];
    float top = v00 * (1.0f - fxx) + v01 * fxx;
    float bot = v10 * (1.0f - fxx) + v11 * fxx;
    float val = top * (1.0f - fyy) + bot * fyy;
    mo[pix] = rintf(val);
  }
}

extern "C" void kernel_launch(void* const* d_in, const int* in_sizes, int n_in,
                              void* d_out, int out_size, void* d_ws, size_t ws_size,
                              hipStream_t stream){
  const float* props  = (const float*)d_in[0];
  const int*   gids   = (const int*)d_in[1];
  const float* gboxes = (const float*)d_in[2];
  const unsigned char* gmask = (const unsigned char*)d_in[3];
  float* out = (float*)d_out;
  float* wsF = (float*)d_ws;
  int*   wsI = (int*)d_ws;

  dtl_zero<<<(out_size + 255)/256, 256, 0, stream>>>(out, out_size);
  dim3 ga(8, BB);
  dtl_score<<<ga, 256, 0, stream>>>(props, gids, gboxes, wsF);
  dim3 gb(8, 2, BB);
  dtl_rank<<<gb, 256, 0, stream>>>(wsF, wsI);
  dtl_emit<<<BB, 256, 0, stream>>>(props, gids, gboxes, wsF, wsI, out);
  dim3 gd(PPOS, BB);
  dtl_masks<<<gd, 256, 0, stream>>>(props, gmask, wsI, out);
}

// Round 5
// 76.170 us; speedup vs baseline: 5.1974x; 1.9398x over previous
//
#include <hip/hip_runtime.h>
#include <stdint.h>

#pragma clang fp contract(off)

#define BB 4
#define NN 2000
#define GG 100
#define HIMG 1024
#define WIMG 1024
#define PPOS 66
#define PNEG 134
#define TT 200
#define MH 28
#define MW 28
#define CHUNK 250

// output offsets (floats): rois [B,200,4], ids [B,200], deltas [B,200,4], masks [B,200,28,28]
#define OFF_ROIS 0
#define OFF_IDS  (BB*TT*4)
#define OFF_DELT (BB*TT*4 + BB*TT)
#define OFF_MASK (BB*TT*4 + BB*TT + BB*TT*4)

// ws layout (float/int units)
#define WS_SCP(b)  ((b)*2048)            // 2000 floats: gated pos scores
#define WS_SCN(b)  (8192 + (b)*2048)     // 2000 floats: gated neg scores
#define WS_CNT     16384                 // ints: [b*4]=npos
#define WS_PIDX(b) (16512 + (b)*128)     // ints: pos slot -> prop idx
#define WS_ASG(b)  (18048 + (b)*128)     // ints: pos slot -> gt idx

__device__ __forceinline__ void tf2x32(uint32_t k0, uint32_t k1, uint32_t& x0, uint32_t& x1){
  uint32_t ks2 = k0 ^ k1 ^ 0x1BD11BDAu;
  x0 += k0; x1 += k1;
#define TFR(r) { x0 += x1; x1 = (x1 << r) | (x1 >> (32 - r)); x1 ^= x0; }
  TFR(13) TFR(15) TFR(26) TFR(6)
  x0 += k1;  x1 += ks2 + 1u;
  TFR(17) TFR(29) TFR(16) TFR(24)
  x0 += ks2; x1 += k0 + 2u;
  TFR(13) TFR(15) TFR(26) TFR(6)
  x0 += k0;  x1 += k1 + 3u;
  TFR(17) TFR(29) TFR(16) TFR(24)
  x0 += k1;  x1 += ks2 + 4u;
  TFR(13) TFR(15) TFR(26) TFR(6)
  x0 += ks2; x1 += k0 + 5u;
#undef TFR
}

__device__ __forceinline__ float u01(uint32_t b){
  return __uint_as_float((b >> 9) | 0x3f800000u) - 1.0f;
}

__device__ __forceinline__ void img_keys(int b, uint32_t& k1a, uint32_t& k1b,
                                         uint32_t& k2a, uint32_t& k2b){
  uint32_t ia = 0u, ib = (uint32_t)b;
  tf2x32(0u, 42u, ia, ib);
  uint32_t a0 = 0u, c0 = 0u; tf2x32(ia, ib, a0, c0);
  uint32_t a1 = 0u, c1 = 1u; tf2x32(ia, ib, a1, c1);
  k1a = a0; k1b = c0; k2a = a1; k2b = c1;
}

__device__ __forceinline__ float iou2(float py1, float px1, float py2, float px2,
                                      float gy1, float gx1, float gy2, float gx2){
  float y1 = fmaxf(py1, gy1);
  float x1 = fmaxf(px1, gx1);
  float y2 = fminf(py2, gy2);
  float x2 = fminf(px2, gx2);
  float inter = fmaxf(x2 - x1, 0.0f) * fmaxf(y2 - y1, 0.0f);
  float a1 = (py2 - py1) * (px2 - px1);
  float a2 = (gy2 - gy1) * (gx2 - gx1);
  return inter / (a1 + a2 - inter);
}

// K1: eligibility + gated scores. grid (8, 4) x 256
__global__ __launch_bounds__(256) void dtl_score(
    const float* __restrict__ props, const int* __restrict__ gids,
    const float* __restrict__ gboxes, float* __restrict__ wsF)
{
  const int cx = blockIdx.x, b = blockIdx.y;
  const int t = threadIdx.x;
  __shared__ float4 sGt[GG];
  __shared__ int    sGid[GG];
  if (t < GG){
    sGt[t]  = ((const float4*)(gboxes + b*GG*4))[t];
    sGid[t] = gids[b*GG + t];
  }
  __syncthreads();
  const int i = cx*CHUNK + t;
  if (t >= CHUNK || i >= NN) return;

  const float4 p = ((const float4*)(props + b*NN*4))[i];
  float best = -1.0f, cbest = -1.0f;
  for (int g = 0; g < GG; ++g){
    float4 gb = sGt[g];
    float v = iou2(p.x, p.y, p.z, p.w, gb.x, gb.y, gb.z, gb.w);
    int id = sGid[g];
    if (id > 0) best = fmaxf(best, v);
    else if (id < 0) cbest = fmaxf(cbest, v);
  }
  bool noc  = cbest < 1e-3f;
  bool posb = best >= 0.5f;
  bool negb = (best < 0.5f) && noc;

  uint32_t k1a, k1b, k2a, k2b;
  img_keys(b, k1a, k1b, k2a, k2b);
  uint32_t a = 0u, c = (uint32_t)i;
  tf2x32(k1a, k1b, a, c);
  uint32_t a2 = 0u, c2 = (uint32_t)i;
  tf2x32(k2a, k2b, a2, c2);
  wsF[WS_SCP(b) + i] = posb ? u01(a ^ c)   : -1.0f;
  wsF[WS_SCN(b) + i] = negb ? u01(a2 ^ c2) : -1.0f;
}

// K2: bucket-rank exact top-k + emit rois/ids/deltas. grid (4) x 256
__global__ __launch_bounds__(256) void dtl_sel(
    const float* __restrict__ props, const int* __restrict__ gids,
    const float* __restrict__ gboxes, const float* __restrict__ wsF,
    int* __restrict__ wsI, float* __restrict__ out)
{
  const int b = blockIdx.x;
  const int t = threadIdx.x;
  const int lane = t & 63, wave = t >> 6;
  __shared__ float  sSc[2][NN];
  __shared__ int    mlist[NN];
  __shared__ int    cnt[256], base_[256], fill[256];
  __shared__ float4 sGt[GG];
  __shared__ int    sGid[GG];
  __shared__ int    slotPos[PPOS], slotNeg[PNEG];
  __shared__ int    sTot[2];

  if (t < GG){
    sGt[t]  = ((const float4*)(gboxes + b*GG*4))[t];
    sGid[t] = gids[b*GG + t];
  }
  for (int j = t; j < NN/4; j += 256){
    ((float4*)sSc[0])[j] = ((const float4*)(wsF + WS_SCP(b)))[j];
    ((float4*)sSc[1])[j] = ((const float4*)(wsF + WS_SCN(b)))[j];
  }

  for (int a = 0; a < 2; ++a){
    const int cap = a ? PNEG : PPOS;
    const float* sc = sSc[a];
    if (t < 256){ cnt[t] = 0; fill[t] = 0; }
    __syncthreads();                 // first pass: also fences sGt/sSc loads
    // histogram (bucket = floor(v*256), monotone in v)
    for (int i = t; i < NN; i += 256){
      float v = sc[i];
      if (v >= 0.0f){
        int k = min((int)(v*256.0f), 255);
        atomicAdd(&cnt[k], 1);
      }
    }
    __syncthreads();
    // exclusive prefix over 256 buckets by wave 0 (4 buckets/lane + shfl scan)
    if (wave == 0){
      int c0 = cnt[lane*4+0], c1 = cnt[lane*4+1], c2 = cnt[lane*4+2], c3 = cnt[lane*4+3];
      int p0 = c0, p1 = p0+c1, p2 = p1+c2, p3 = p2+c3;
      int inc = p3;
      for (int off = 1; off < 64; off <<= 1){
        int v = __shfl_up(inc, off);
        if (lane >= off) inc += v;
      }
      int excl = inc - p3;
      base_[lane*4+0] = excl;
      base_[lane*4+1] = excl + p0;
      base_[lane*4+2] = excl + p1;
      base_[lane*4+3] = excl + p2;
      if (lane == 63) sTot[a] = inc;
    }
    __syncthreads();
    // bucket-sorted member list
    for (int i = t; i < NN; i += 256){
      float v = sc[i];
      if (v >= 0.0f){
        int k = min((int)(v*256.0f), 255);
        int pos = base_[k] + atomicAdd(&fill[k], 1);
        mlist[pos] = i;
      }
    }
    __syncthreads();
    // exact slot = (#eligible in higher buckets) + within-bucket rank
    const int tot = sTot[a];
    int* slotArr = a ? slotNeg : slotPos;
    for (int i = t; i < NN; i += 256){
      float v = sc[i];
      if (v >= 0.0f){
        int k = min((int)(v*256.0f), 255);
        int S = tot - base_[k] - cnt[k];
        if (S < cap){
          int wr = 0;
          const int s0 = base_[k], e0 = s0 + cnt[k];
          for (int m = s0; m < e0; ++m){
            int j = mlist[m];
            float vj = sc[j];
            wr += (int)((vj > v) | ((vj == v) & (j < i)));
          }
          int slot = S + wr;
          if (slot < cap) slotArr[slot] = i;
        }
      }
    }
    __syncthreads();
  }

  const int npos = min(sTot[0], PPOS);
  int tgt = (int)((float)npos / 0.33f) - npos;  // exact fp32 semantics of reference
  if (tgt < 0) tgt = 0;
  const int nneg = min(min(sTot[1], tgt), PNEG);
  if (t == 0) wsI[WS_CNT + b*4] = npos;

  const float* pb = props + b*NN*4;
  if (t < TT){
    float r0=0,r1=0,r2=0,r3=0, idv=0, d0=0,d1=0,d2=0,d3=0;
    if (t < PPOS){
      if (t < npos){
        int idx = slotPos[t];
        float4 p = ((const float4*)pb)[idx];
        float bestv = -2.0f; int bg = 0;
        for (int g = 0; g < GG; ++g){
          float4 gb = sGt[g];
          float v = (sGid[g] > 0) ? iou2(p.x,p.y,p.z,p.w, gb.x,gb.y,gb.z,gb.w) : -1.0f;
          if (v > bestv){ bestv = v; bg = g; }
        }
        float4 gt = sGt[bg];
        float h  = p.z - p.x,        w  = p.w - p.y;
        float cy = p.x + 0.5f*h,     cx = p.y + 0.5f*w;
        float gh = gt.z - gt.x,      gw = gt.w - gt.y;
        float gcy = gt.x + 0.5f*gh,  gcx = gt.y + 0.5f*gw;
        r0 = p.x; r1 = p.y; r2 = p.z; r3 = p.w;
        idv = (float)sGid[bg];
        d0 = ((gcy - cy) / h) / 0.1f;
        d1 = ((gcx - cx) / w) / 0.1f;
        d2 = logf(gh / h) / 0.2f;
        d3 = logf(gw / w) / 0.2f;
        wsI[WS_PIDX(b) + t] = idx;
        wsI[WS_ASG(b) + t]  = bg;
      }
    } else {
      int pn = t - PPOS;
      if (pn < nneg){
        int idx = slotNeg[pn];
        float4 p = ((const float4*)pb)[idx];
        r0 = p.x; r1 = p.y; r2 = p.z; r3 = p.w;
      }
    }
    float* ro = out + OFF_ROIS + (b*TT + t)*4;
    ro[0] = r0; ro[1] = r1; ro[2] = r2; ro[3] = r3;
    out[OFF_IDS + b*TT + t] = idv;
    float* de = out + OFF_DELT + (b*TT + t)*4;
    de[0] = d0; de[1] = d1; de[2] = d2; de[3] = d3;
  }
}

// K3: mask crop+resize, zero-fill invalid/negative slots. grid (200, 4) x 256
__global__ __launch_bounds__(256) void dtl_masks(
    const float* __restrict__ props, const unsigned char* __restrict__ gmask,
    const int* __restrict__ wsI, float* __restrict__ out)
{
  const int p = blockIdx.x;
  const int b = blockIdx.y;
  const int t = threadIdx.x;
  const int npos = wsI[WS_CNT + b*4];
  float* mo = out + OFF_MASK + (size_t)(b*TT + p) * (MH*MW);
  if (p >= npos){
    for (int pix = t; pix < MH*MW; pix += 256) mo[pix] = 0.0f;
    return;
  }
  __shared__ int   iy0[MH], iy1[MH], ix0[MW], ix1[MW];
  __shared__ float fy[MH], fx[MW];
  __shared__ float sbox[4];
  if (t == 0){
    int idx = wsI[WS_PIDX(b) + p];
    sbox[0] = props[(b*NN + idx)*4 + 0];
    sbox[1] = props[(b*NN + idx)*4 + 1];
    sbox[2] = props[(b*NN + idx)*4 + 2];
    sbox[3] = props[(b*NN + idx)*4 + 3];
  }
  __syncthreads();
  if (t < MH){
    float y1 = sbox[0], y2 = sbox[2];
    float stepy = (y2 - y1) * 1023.0f / 27.0f;
    float ys = y1 * 1023.0f + (float)t * stepy;
    float y0f = floorf(ys);
    iy0[t] = (int)fminf(fmaxf(y0f, 0.0f), 1023.0f);
    iy1[t] = (int)fminf(fmaxf(y0f + 1.0f, 0.0f), 1023.0f);
    fy[t] = ys - y0f;
    float x1 = sbox[1], x2 = sbox[3];
    float stepx = (x2 - x1) * 1023.0f / 27.0f;
    float xs = x1 * 1023.0f + (float)t * stepx;
    float x0f = floorf(xs);
    ix0[t] = (int)fminf(fmaxf(x0f, 0.0f), 1023.0f);
    ix1[t] = (int)fminf(fmaxf(x0f + 1.0f, 0.0f), 1023.0f);
    fx[t] = xs - x0f;
  }
  __syncthreads();
  const int g = wsI[WS_ASG(b) + p];
  const unsigned char* mb = gmask + (size_t)b * HIMG * WIMG * GG + g;
  for (int pix = t; pix < MH*MW; pix += 256){
    int r = pix / MW, c = pix - r*MW;
    size_t ro0 = (size_t)iy0[r] * WIMG;
    size_t ro1 = (size_t)iy1[r] * WIMG;
    float v00 = mb[(ro0 + (size_t)ix0[c]) * GG] ? 1.0f : 0.0f;
    float v01 = mb[(ro0 + (size_t)ix1[c]) * GG] ? 1.0f : 0.0f;
    float v10 = mb[(ro1 + (size_t)ix0[c]) * GG] ? 1.0f : 0.0f;
    float v11 = mb[(ro1 + (size_t)ix1[c]) * GG] ? 1.0f : 0.0f;
    float fxx = fx[c], fyy = fy[r];
    float top = v00 * (1.0f - fxx) + v01 * fxx;
    float bot = v10 * (1.0f - fxx) + v11 * fxx;
    float val = top * (1.0f - fyy) + bot * fyy;
    mo[pix] = rintf(val);
  }
}

extern "C" void kernel_launch(void* const* d_in, const int* in_sizes, int n_in,
                              void* d_out, int out_size, void* d_ws, size_t ws_size,
                              hipStream_t stream){
  const float* props  = (const float*)d_in[0];
  const int*   gids   = (const int*)d_in[1];
  const float* gboxes = (const float*)d_in[2];
  const unsigned char* gmask = (const unsigned char*)d_in[3];
  float* out = (float*)d_out;
  float* wsF = (float*)d_ws;
  int*   wsI = (int*)d_ws;

  dim3 ga(8, BB);
  dtl_score<<<ga, 256, 0, stream>>>(props, gids, gboxes, wsF);
  dtl_sel<<<BB, 256, 0, stream>>>(props, gids, gboxes, wsF, wsI, out);
  dim3 gd(TT, BB);
  dtl_masks<<<gd, 256, 0, stream>>>(props, gmask, wsI, out);
}